// Round 1
// baseline (1640.480 us; speedup 1.0000x reference)
//
#include <hip/hip_runtime.h>
#include <math.h>

// Problem constants (fixed by the reference).
#define NROWS 12288

__device__ __forceinline__ float elu_f(float x) { return x > 0.f ? x : expm1f(x); }

// ---------------------------------------------------------------------------
// enc1: out[m,0:32] = elu(concat(one_hot[m,0:20], features[m,0:44]) @ We1 + be1)
// one thread per 4 outputs (float4), 8 o4-groups per row.
// ---------------------------------------------------------------------------
__global__ __launch_bounds__(256) void enc1_kernel(
    const float* __restrict__ oh, const float* __restrict__ ft,
    const float* __restrict__ W, const float* __restrict__ b,
    float* __restrict__ out)
{
    int id = blockIdx.x * 256 + threadIdx.x;
    if (id >= NROWS * 8) return;
    int o4 = id & 7;
    int m  = id >> 3;
    const float4* W4 = reinterpret_cast<const float4*>(W);
    float4 acc = reinterpret_cast<const float4*>(b)[o4];
    const float* ohr = oh + m * 20;
    const float* ftr = ft + m * 44;
#pragma unroll
    for (int i = 0; i < 64; ++i) {
        float x = (i < 20) ? ohr[i] : ftr[i - 20];
        float4 w = W4[i * 8 + o4];
        acc.x = fmaf(x, w.x, acc.x);
        acc.y = fmaf(x, w.y, acc.y);
        acc.z = fmaf(x, w.z, acc.z);
        acc.w = fmaf(x, w.w, acc.w);
    }
    acc.x = elu_f(acc.x); acc.y = elu_f(acc.y);
    acc.z = elu_f(acc.z); acc.w = elu_f(acc.w);
    reinterpret_cast<float4*>(out)[id] = acc;
}

// ---------------------------------------------------------------------------
// Generic dense linear: out[m, o] = (bias?) + sum_i in[m,i] * W[i,o], optional ELU.
// One thread per float4 of output.
// ---------------------------------------------------------------------------
template <int IN, int OUT, bool BIAS, bool ACT_ELU>
__global__ __launch_bounds__(256) void linear4_kernel(
    const float* __restrict__ in, const float* __restrict__ W,
    const float* __restrict__ b, float* __restrict__ out)
{
    constexpr int O4 = OUT / 4;
    int id = blockIdx.x * 256 + threadIdx.x;
    if (id >= NROWS * O4) return;
    int o4 = id % O4;
    int m  = id / O4;
    float4 acc;
    if (BIAS) acc = reinterpret_cast<const float4*>(b)[o4];
    else      acc = make_float4(0.f, 0.f, 0.f, 0.f);
    const float*  ip = in + (size_t)m * IN;
    const float4* W4 = reinterpret_cast<const float4*>(W);
#pragma unroll 8
    for (int i = 0; i < IN; ++i) {
        float  x = ip[i];
        float4 w = W4[i * O4 + o4];
        acc.x = fmaf(x, w.x, acc.x);
        acc.y = fmaf(x, w.y, acc.y);
        acc.z = fmaf(x, w.z, acc.z);
        acc.w = fmaf(x, w.w, acc.w);
    }
    if (ACT_ELU) {
        acc.x = elu_f(acc.x); acc.y = elu_f(acc.y);
        acc.z = elu_f(acc.z); acc.w = elu_f(acc.w);
    }
    reinterpret_cast<float4*>(out)[id] = acc;
}

// ---------------------------------------------------------------------------
// Aggregation: part[seg][m, o] = sum_{k in seg} A[m,k] * h[k,o]
// Split-K register-tiled fp32 GEMM. BM=128 rows, BK=64, 256 threads.
// A tile staged TRANSPOSED in LDS (+4 pad -> 16B-aligned rows, conflict-free
// b128 a-fragment reads). h tile staged linear. Per-thread TMxTN outer product.
// Partials: plain stores to disjoint slabs (no atomics, no zero-init needed).
// ---------------------------------------------------------------------------
template <int OUT, int TM, int TN, int SPLIT>
__global__ __launch_bounds__(256) void agg_kernel(
    const float* __restrict__ A, const float* __restrict__ h,
    float* __restrict__ part)
{
    constexpr int BK    = 64;
    constexpr int TCOLS = OUT / TN;
    constexpr int TROWS = 256 / TCOLS;
    constexpr int BM    = TROWS * TM;      // 128 for all configs
    constexpr int MT    = NROWS / BM;      // 96
    constexpr int SEG   = NROWS / SPLIT;
    constexpr int HV    = BK * OUT / 4;    // float4s in h tile
    constexpr int HL    = (HV + 255) / 256;

    __shared__ float At[BK][BM + 4];       // transposed A tile
    __shared__ float Hs[BK][OUT];

    const int tid  = threadIdx.x;
    const int mt   = blockIdx.x % MT;
    const int seg  = blockIdx.x / MT;
    const int m0   = mt * BM;
    const int kb   = seg * SEG;
    const int tcol = tid % TCOLS;
    const int trow = tid / TCOLS;

    const int lr = tid >> 2;         // 0..63 : row within 64-row pass
    const int lc = (tid & 3) * 16;   // 0,16,32,48 : col base (16 floats each)

    float acc[TM][TN];
#pragma unroll
    for (int i = 0; i < TM; ++i)
#pragma unroll
        for (int j = 0; j < TN; ++j) acc[i][j] = 0.f;

    for (int k0 = kb; k0 < kb + SEG; k0 += BK) {
        // ---- issue all global loads into registers first (latency overlap)
        float4 av[BM / 64][4];
#pragma unroll
        for (int p = 0; p < BM / 64; ++p) {
            const float4* src = reinterpret_cast<const float4*>(
                A + (size_t)(m0 + p * 64 + lr) * NROWS + k0 + lc);
            av[p][0] = src[0]; av[p][1] = src[1];
            av[p][2] = src[2]; av[p][3] = src[3];
        }
        float4 hv[HL];
        const float4* hsrc = reinterpret_cast<const float4*>(h + (size_t)k0 * OUT);
#pragma unroll
        for (int i = 0; i < HL; ++i)
            if (HV >= 256 * (i + 1) || i * 256 + tid < HV) hv[i] = hsrc[i * 256 + tid];

        __syncthreads();   // previous tile's LDS reads complete

        // ---- LDS writes (A transposed)
#pragma unroll
        for (int p = 0; p < BM / 64; ++p) {
            int r = p * 64 + lr;
#pragma unroll
            for (int v = 0; v < 4; ++v) {
                At[lc + v * 4 + 0][r] = av[p][v].x;
                At[lc + v * 4 + 1][r] = av[p][v].y;
                At[lc + v * 4 + 2][r] = av[p][v].z;
                At[lc + v * 4 + 3][r] = av[p][v].w;
            }
        }
        float4* hdst = reinterpret_cast<float4*>(&Hs[0][0]);
#pragma unroll
        for (int i = 0; i < HL; ++i)
            if (HV >= 256 * (i + 1) || i * 256 + tid < HV) hdst[i * 256 + tid] = hv[i];

        __syncthreads();   // tile visible

        // ---- inner product
#pragma unroll 8
        for (int k = 0; k < BK; ++k) {
            float af[TM];
            if constexpr (TM == 4) {
                float4 t = *reinterpret_cast<const float4*>(&At[k][trow * 4]);
                af[0] = t.x; af[1] = t.y; af[2] = t.z; af[3] = t.w;
            } else if constexpr (TM == 2) {
                float2 t = *reinterpret_cast<const float2*>(&At[k][trow * 2]);
                af[0] = t.x; af[1] = t.y;
            } else {
                af[0] = At[k][trow];
            }
            float hf[TN];
            if constexpr (TN == 8) {
                float4 a = *reinterpret_cast<const float4*>(&Hs[k][tcol * 8]);
                float4 c = *reinterpret_cast<const float4*>(&Hs[k][tcol * 8 + 4]);
                hf[0] = a.x; hf[1] = a.y; hf[2] = a.z; hf[3] = a.w;
                hf[4] = c.x; hf[5] = c.y; hf[6] = c.z; hf[7] = c.w;
            } else if constexpr (TN == 4) {
                float4 a = *reinterpret_cast<const float4*>(&Hs[k][tcol * 4]);
                hf[0] = a.x; hf[1] = a.y; hf[2] = a.z; hf[3] = a.w;
            } else {
                float2 a = *reinterpret_cast<const float2*>(&Hs[k][tcol * 2]);
                hf[0] = a.x; hf[1] = a.y;
            }
#pragma unroll
            for (int i = 0; i < TM; ++i)
#pragma unroll
                for (int j = 0; j < TN; ++j)
                    acc[i][j] = fmaf(af[i], hf[j], acc[i][j]);
        }
    }

    // ---- write partials (exclusive region per block)
    float* pd = part + (size_t)seg * ((size_t)NROWS * OUT);
#pragma unroll
    for (int i = 0; i < TM; ++i) {
        int m = m0 + trow * TM + i;
        float* row = pd + (size_t)m * OUT + tcol * TN;
        if constexpr (TN == 8) {
            *reinterpret_cast<float4*>(row)     = make_float4(acc[i][0], acc[i][1], acc[i][2], acc[i][3]);
            *reinterpret_cast<float4*>(row + 4) = make_float4(acc[i][4], acc[i][5], acc[i][6], acc[i][7]);
        } else if constexpr (TN == 4) {
            *reinterpret_cast<float4*>(row) = make_float4(acc[i][0], acc[i][1], acc[i][2], acc[i][3]);
        } else {
            *reinterpret_cast<float2*>(row) = make_float2(acc[i][0], acc[i][1]);
        }
    }
}

// ---------------------------------------------------------------------------
// Reduce split-K partials, add bias, ELU -> next x.
// ---------------------------------------------------------------------------
template <int OUT, int SPLIT>
__global__ __launch_bounds__(256) void reduce_kernel(
    const float* __restrict__ part, const float* __restrict__ b,
    float* __restrict__ out)
{
    constexpr int O4 = OUT / 4;
    int id = blockIdx.x * 256 + threadIdx.x;
    if (id >= NROWS * O4) return;
    const float4* p4 = reinterpret_cast<const float4*>(part);
    float4 s = p4[id];
#pragma unroll
    for (int t = 1; t < SPLIT; ++t) {
        float4 v = p4[(size_t)t * (NROWS * O4) + id];
        s.x += v.x; s.y += v.y; s.z += v.z; s.w += v.w;
    }
    float4 bb = reinterpret_cast<const float4*>(b)[id % O4];
    s.x = elu_f(s.x + bb.x); s.y = elu_f(s.y + bb.y);
    s.z = elu_f(s.z + bb.z); s.w = elu_f(s.w + bb.w);
    reinterpret_cast<float4*>(out)[id] = s;
}

// ---------------------------------------------------------------------------
// Layer-5 reduce fused with the whole final MLP + sigmoid. One thread per row.
// ---------------------------------------------------------------------------
__global__ __launch_bounds__(256) void reduce5_final_kernel(
    const float* __restrict__ part, const float* __restrict__ bg,
    const float* __restrict__ Wf1, const float* __restrict__ bf1,
    const float* __restrict__ Wf2, const float* __restrict__ bf2,
    const float* __restrict__ Wf3, const float* __restrict__ bf3,
    float* __restrict__ out)
{
    int m = blockIdx.x * 256 + threadIdx.x;
    if (m >= NROWS) return;
    const float4* p4 = reinterpret_cast<const float4*>(part);
    float4 s = p4[m];
#pragma unroll
    for (int t = 1; t < 16; ++t) {
        float4 v = p4[(size_t)t * NROWS + m];
        s.x += v.x; s.y += v.y; s.z += v.z; s.w += v.w;
    }
    float x0 = elu_f(s.x + bg[0]);
    float x1 = elu_f(s.y + bg[1]);
    float x2 = elu_f(s.z + bg[2]);
    float x3 = elu_f(s.w + bg[3]);

    float t1[8];
#pragma unroll
    for (int o = 0; o < 8; ++o) {
        float a = bf1[o];
        a = fmaf(x0, Wf1[0 * 8 + o], a);
        a = fmaf(x1, Wf1[1 * 8 + o], a);
        a = fmaf(x2, Wf1[2 * 8 + o], a);
        a = fmaf(x3, Wf1[3 * 8 + o], a);
        t1[o] = elu_f(a);
    }
    float t2[4];
#pragma unroll
    for (int o = 0; o < 4; ++o) {
        float a = bf2[o];
#pragma unroll
        for (int i = 0; i < 8; ++i) a = fmaf(t1[i], Wf2[i * 4 + o], a);
        t2[o] = elu_f(a);
    }
    float z = bf3[0];
#pragma unroll
    for (int i = 0; i < 4; ++i) z = fmaf(t2[i], Wf3[i], z);
    out[m] = 1.f / (1.f + expf(-z));
}

// ---------------------------------------------------------------------------
// Host launcher
// ---------------------------------------------------------------------------
static inline dim3 grid_for(int threads) { return dim3((threads + 255) / 256); }

extern "C" void kernel_launch(void* const* d_in, const int* in_sizes, int n_in,
                              void* d_out, int out_size, void* d_ws, size_t ws_size,
                              hipStream_t stream)
{
    (void)in_sizes; (void)n_in; (void)out_size; (void)ws_size;

    const float* one_hot  = (const float*)d_in[0];
    const float* features = (const float*)d_in[1];
    // d_in[2] = gemme_features: unused by the reference.
    const float* A    = (const float*)d_in[3];
    const float* We1  = (const float*)d_in[4];  const float* be1 = (const float*)d_in[5];
    const float* We2  = (const float*)d_in[6];  const float* be2 = (const float*)d_in[7];
    const float* We3  = (const float*)d_in[8];  const float* be3 = (const float*)d_in[9];
    const float* Wg1  = (const float*)d_in[10]; const float* bg1 = (const float*)d_in[11];
    const float* Wg2  = (const float*)d_in[12]; const float* bg2 = (const float*)d_in[13];
    const float* Wg3  = (const float*)d_in[14]; const float* bg3 = (const float*)d_in[15];
    const float* Wg4  = (const float*)d_in[16]; const float* bg4 = (const float*)d_in[17];
    const float* Wg5  = (const float*)d_in[18]; const float* bg5 = (const float*)d_in[19];
    const float* Wf1  = (const float*)d_in[20]; const float* bf1 = (const float*)d_in[21];
    const float* Wf2  = (const float*)d_in[22]; const float* bf2 = (const float*)d_in[23];
    const float* Wf3  = (const float*)d_in[24]; const float* bf3 = (const float*)d_in[25];
    float* out = (float*)d_out;

    // Workspace layout (floats): bufA[N*128] bufB[N*128] hb[N*64] part[12*N*64]
    // total = N*1088 floats = 53.5 MB
    float* bufA = (float*)d_ws;
    float* bufB = bufA + (size_t)NROWS * 128;
    float* hb   = bufB + (size_t)NROWS * 128;
    float* part = hb   + (size_t)NROWS * 64;

    // Encoder
    enc1_kernel<<<grid_for(NROWS * 8), 256, 0, stream>>>(one_hot, features, We1, be1, bufB);
    linear4_kernel<32, 64, true, true><<<grid_for(NROWS * 16), 256, 0, stream>>>(bufB, We2, be2, bufA);
    linear4_kernel<64, 128, true, true><<<grid_for(NROWS * 32), 256, 0, stream>>>(bufA, We3, be3, bufB);

    // gconv 1: 128 -> 64
    linear4_kernel<128, 64, false, false><<<grid_for(NROWS * 16), 256, 0, stream>>>(bufB, Wg1, nullptr, hb);
    agg_kernel<64, 4, 8, 12><<<dim3(96 * 12), 256, 0, stream>>>(A, hb, part);
    reduce_kernel<64, 12><<<grid_for(NROWS * 16), 256, 0, stream>>>(part, bg1, bufA);

    // gconv 2: 64 -> 32
    linear4_kernel<64, 32, false, false><<<grid_for(NROWS * 8), 256, 0, stream>>>(bufA, Wg2, nullptr, hb);
    agg_kernel<32, 2, 8, 16><<<dim3(96 * 16), 256, 0, stream>>>(A, hb, part);
    reduce_kernel<32, 16><<<grid_for(NROWS * 8), 256, 0, stream>>>(part, bg2, bufB);

    // gconv 3: 32 -> 16
    linear4_kernel<32, 16, false, false><<<grid_for(NROWS * 4), 256, 0, stream>>>(bufB, Wg3, nullptr, hb);
    agg_kernel<16, 2, 4, 16><<<dim3(96 * 16), 256, 0, stream>>>(A, hb, part);
    reduce_kernel<16, 16><<<grid_for(NROWS * 4), 256, 0, stream>>>(part, bg3, bufA);

    // gconv 4: 16 -> 8
    linear4_kernel<16, 8, false, false><<<grid_for(NROWS * 2), 256, 0, stream>>>(bufA, Wg4, nullptr, hb);
    agg_kernel<8, 1, 4, 16><<<dim3(96 * 16), 256, 0, stream>>>(A, hb, part);
    reduce_kernel<8, 16><<<grid_for(NROWS * 2), 256, 0, stream>>>(part, bg4, bufB);

    // gconv 5: 8 -> 4 (+ fused final MLP + sigmoid)
    linear4_kernel<8, 4, false, false><<<grid_for(NROWS), 256, 0, stream>>>(bufB, Wg5, nullptr, hb);
    agg_kernel<4, 1, 2, 16><<<dim3(96 * 16), 256, 0, stream>>>(A, hb, part);
    reduce5_final_kernel<<<grid_for(NROWS), 256, 0, stream>>>(part, bg5, Wf1, bf1, Wf2, bf2, Wf3, bf3, out);
}